// Round 1
// baseline (83.839 us; speedup 1.0000x reference)
//
#include <hip/hip_runtime.h>
#include <math.h>

#define DIMK 2048
#define NEXP 64
#define BM 64
#define BK 32
#define NWAVE 4
#define KPW (DIMK / NWAVE)   // 512 k per wave
#define NCHUNK (KPW / BK)    // 16 chunks per wave
#define LSTR 68              // padded float stride per k-row (68*4B, 16B aligned, bank-spread)
#define WBUF (2 * BK * LSTR) // floats of LDS per wave (A tile + W tile)

__device__ __forceinline__ bool gt_pair(float v, int i, float v2, int i2) {
    return (v > v2) || (v == v2 && i < i2);
}

__global__ __launch_bounds__(256)
void SwitchRouter_43078521979510_kernel(const float* __restrict__ x,
                                        const float* __restrict__ Wt,
                                        const float* __restrict__ bias,
                                        float* __restrict__ out, int M)
{
    __shared__ float lds[NWAVE * WBUF];  // 4*2*32*68 floats = 69632 B

    const int t    = threadIdx.x;
    const int wave = t >> 6;
    const int lane = t & 63;
    const int lr   = lane >> 3;  // 0..7 (row group)
    const int lc   = lane & 7;   // 0..7 (expert group)
    const int r0   = blockIdx.x * BM;

    const int aoff = wave * WBUF;
    const int woff = aoff + BK * LSTR;

    float acc[8][8];
#pragma unroll
    for (int i = 0; i < 8; ++i)
#pragma unroll
        for (int j = 0; j < 8; ++j) acc[i][j] = 0.f;

    const int rr = lane >> 3;        // staging row/expert sub-index 0..7
    const int kk = (lane & 7) * 4;   // staging k offset 0,4,...,28

    // register prefetch of chunk 0 (A: 8 float4, W: 8 float4)
    float4 pa[8], pw[8];
    {
        const int kb = wave * KPW;
#pragma unroll
        for (int c2 = 0; c2 < 8; ++c2) {
            pa[c2] = *(const float4*)&x [(size_t)(r0 + 8 * c2 + rr) * DIMK + kb + kk];
            pw[c2] = *(const float4*)&Wt[(size_t)(8 * c2 + rr) * DIMK + kb + kk];
        }
    }

    for (int c = 0; c < NCHUNK; ++c) {
        // ---- store prefetched chunk to LDS (transposed [k][r], stride 68) ----
#pragma unroll
        for (int c2 = 0; c2 < 8; ++c2) {
            const int row = 8 * c2 + rr;
            float4 va = pa[c2], vw = pw[c2];
            lds[aoff + (kk + 0) * LSTR + row] = va.x;
            lds[aoff + (kk + 1) * LSTR + row] = va.y;
            lds[aoff + (kk + 2) * LSTR + row] = va.z;
            lds[aoff + (kk + 3) * LSTR + row] = va.w;
            lds[woff + (kk + 0) * LSTR + row] = vw.x;
            lds[woff + (kk + 1) * LSTR + row] = vw.y;
            lds[woff + (kk + 2) * LSTR + row] = vw.z;
            lds[woff + (kk + 3) * LSTR + row] = vw.w;
        }
        // ---- issue next chunk's global loads (latency hidden under compute) ----
        if (c + 1 < NCHUNK) {
            const int kb2 = wave * KPW + (c + 1) * BK;
#pragma unroll
            for (int c2 = 0; c2 < 8; ++c2) {
                pa[c2] = *(const float4*)&x [(size_t)(r0 + 8 * c2 + rr) * DIMK + kb2 + kk];
                pw[c2] = *(const float4*)&Wt[(size_t)(8 * c2 + rr) * DIMK + kb2 + kk];
            }
        }
        // ---- inner product over this chunk ----
#pragma unroll 8
        for (int k = 0; k < BK; ++k) {
            const float4 a0 = *(const float4*)&lds[aoff + k * LSTR + 8 * lr];
            const float4 a1 = *(const float4*)&lds[aoff + k * LSTR + 8 * lr + 4];
            const float4 w0 = *(const float4*)&lds[woff + k * LSTR + 8 * lc];
            const float4 w1 = *(const float4*)&lds[woff + k * LSTR + 8 * lc + 4];
            const float av[8] = {a0.x, a0.y, a0.z, a0.w, a1.x, a1.y, a1.z, a1.w};
            const float wv[8] = {w0.x, w0.y, w0.z, w0.w, w1.x, w1.y, w1.z, w1.w};
#pragma unroll
            for (int i = 0; i < 8; ++i)
#pragma unroll
                for (int j = 0; j < 8; ++j)
                    acc[i][j] = fmaf(av[i], wv[j], acc[i][j]);
        }
    }

    // ---- cross-wave tree reduction of partial 64x64 tiles ----
    __syncthreads();
    float4* red = (float4*)lds;  // buffers: [2][64 rows][17 float4] (XOR-swizzled cols)

    if (wave >= 2) {
        const int buf = wave - 2;
#pragma unroll
        for (int i = 0; i < 8; ++i)
#pragma unroll
            for (int g = 0; g < 2; ++g) {
                const int colf4 = (2 * lc + g) ^ lr;
                red[(size_t)buf * 64 * 17 + (8 * lr + i) * 17 + colf4] =
                    make_float4(acc[i][4 * g + 0], acc[i][4 * g + 1],
                                acc[i][4 * g + 2], acc[i][4 * g + 3]);
            }
    }
    __syncthreads();
    if (wave < 2) {
        const int buf = wave;
#pragma unroll
        for (int i = 0; i < 8; ++i)
#pragma unroll
            for (int g = 0; g < 2; ++g) {
                const int colf4 = (2 * lc + g) ^ lr;
                float4 v = red[(size_t)buf * 64 * 17 + (8 * lr + i) * 17 + colf4];
                acc[i][4 * g + 0] += v.x;
                acc[i][4 * g + 1] += v.y;
                acc[i][4 * g + 2] += v.z;
                acc[i][4 * g + 3] += v.w;
            }
    }
    __syncthreads();
    if (wave == 1) {
#pragma unroll
        for (int i = 0; i < 8; ++i)
#pragma unroll
            for (int g = 0; g < 2; ++g) {
                const int colf4 = (2 * lc + g) ^ lr;
                red[(8 * lr + i) * 17 + colf4] =
                    make_float4(acc[i][4 * g + 0], acc[i][4 * g + 1],
                                acc[i][4 * g + 2], acc[i][4 * g + 3]);
            }
    }
    __syncthreads();
    if (wave == 0) {
#pragma unroll
        for (int i = 0; i < 8; ++i)
#pragma unroll
            for (int g = 0; g < 2; ++g) {
                const int colf4 = (2 * lc + g) ^ lr;
                float4 v = red[(8 * lr + i) * 17 + colf4];
                acc[i][4 * g + 0] += v.x;
                acc[i][4 * g + 1] += v.y;
                acc[i][4 * g + 2] += v.z;
                acc[i][4 * g + 3] += v.w;
            }

        // ---- epilogue: bias + top-2 + softmax values, one row per (lr,i) ----
        float bvals[8];
#pragma unroll
        for (int j = 0; j < 8; ++j) bvals[j] = bias[8 * lc + j];

#pragma unroll
        for (int i = 0; i < 8; ++i) {
            float l[8];
#pragma unroll
            for (int j = 0; j < 8; ++j) l[j] = acc[i][j] + bvals[j];

            // lane-local stable top-2 (ascending index scan => lax.top_k tie rule)
            float v0 = l[0];
            int   i0 = 8 * lc;
            float v1 = -INFINITY;
            int   i1 = -1;
#pragma unroll
            for (int j = 1; j < 8; ++j) {
                const float lv = l[j];
                const int   e  = 8 * lc + j;
                if (lv > v0) { v1 = v0; i1 = i0; v0 = lv; i0 = e; }
                else if (lv > v1) { v1 = lv; i1 = e; }
            }
            // merge across the 8 lanes of this row group
#pragma unroll
            for (int m = 1; m <= 4; m <<= 1) {
                const float ov0 = __shfl_xor(v0, m);
                const int   oi0 = __shfl_xor(i0, m);
                const float ov1 = __shfl_xor(v1, m);
                const int   oi1 = __shfl_xor(i1, m);
                if (gt_pair(ov0, oi0, v0, i0)) {
                    if (gt_pair(v0, i0, ov1, oi1)) { v1 = v0; i1 = i0; }
                    else                           { v1 = ov1; i1 = oi1; }
                    v0 = ov0; i0 = oi0;
                } else if (gt_pair(ov0, oi0, v1, i1)) {
                    v1 = ov0; i1 = oi0;
                }
            }
            // softmax denominator over all 64 experts (row max = v0)
            float d = 0.f;
#pragma unroll
            for (int j = 0; j < 8; ++j) d += expf(l[j] - v0);
#pragma unroll
            for (int m = 1; m <= 4; m <<= 1) d += __shfl_xor(d, m);

            if (lc == 0) {
                const int R = r0 + 8 * lr + i;
                out[2 * R]     = (float)i0;
                out[2 * R + 1] = (float)i1;
                out[2 * M + 2 * R]     = 1.f / d;           // exp(v0-v0)/d
                out[2 * M + 2 * R + 1] = expf(v1 - v0) / d;
            }
        }
    }
}

extern "C" void kernel_launch(void* const* d_in, const int* in_sizes, int n_in,
                              void* d_out, int out_size, void* d_ws, size_t ws_size,
                              hipStream_t stream) {
    const float* x  = (const float*)d_in[0];
    const float* W  = (const float*)d_in[1];
    const float* b  = (const float*)d_in[2];
    float* out = (float*)d_out;
    const int M = in_sizes[0] / DIMK;  // 16384 rows
    const int grid = M / BM;           // 256 blocks
    SwitchRouter_43078521979510_kernel<<<grid, 256, 0, stream>>>(x, W, b, out, M);
}

// Round 2
// 37.301 us; speedup vs baseline: 2.2476x; 2.2476x over previous
//
#include <hip/hip_runtime.h>
#include <math.h>

typedef _Float16 half8 __attribute__((ext_vector_type(8)));
typedef float floatx16 __attribute__((ext_vector_type(16)));

#define DIMK 2048
#define NEXP 64
#define BM 32                 // rows per block
#define KSPLIT 4              // waves per block, k-split
#define KPW (DIMK / KSPLIT)   // 512 k per wave
#define CHUNK 64              // k per staged chunk
#define NCHUNK (KPW / CHUNK)  // 8 chunks per wave
#define KSTEP 16              // k per MFMA step (32x32x16)
#define NKS (CHUNK / KSTEP)   // 4 ksteps per chunk

// ---------------- W pre-split kernel ----------------
// ws layout (halfs): [kb8 = k/8][limb][e][k%8]  -> block of 512 halfs per (kb8,limb)
__global__ void SwitchRouter_wsplit(const float* __restrict__ W, _Float16* __restrict__ ws) {
    int t = blockIdx.x * 256 + threadIdx.x;
    if (t >= NEXP * DIMK) return;
    int e = t >> 11, k = t & (DIMK - 1);
    float w = W[e * DIMK + k];
    _Float16 h0 = (_Float16)w;
    _Float16 h1 = (_Float16)(w - (float)h0);
    int kb8 = k >> 3, kj = k & 7;
    ws[(((kb8 * 2 + 0) << 9) + (e << 3) + kj)] = h0;
    ws[(((kb8 * 2 + 1) << 9) + (e << 3) + kj)] = h1;
}

__device__ __forceinline__ bool gt_pair(float v, int i, float v2, int i2) {
    return (v > v2) || (v == v2 && i < i2);
}

// stage one 32-row x 64-k fp32 chunk into LDS via global_load_lds (linear dest,
// inverse-swizzled source; read side applies the same XOR swizzle)
__device__ __forceinline__ void stage_chunk(const float* xg, float* dst, int lane) {
#pragma unroll
    for (int j = 0; j < 8; ++j) {
        int rowj = j * 4 + (lane >> 4);
        const float* src = xg + (size_t)rowj * DIMK + (((lane & 15) ^ (rowj & 15)) << 2);
        __builtin_amdgcn_global_load_lds(
            (const __attribute__((address_space(1))) void*)src,
            (__attribute__((address_space(3))) void*)(dst + j * 256),
            16, 0, 0);
    }
}

__device__ __forceinline__ half8 ldw(const _Float16* wsp, int kglob0, int half_, int et, int limb, int row) {
    int kb8 = (kglob0 >> 3) + half_;
    return *(const half8*)(wsp + (((size_t)(kb8 * 2 + limb) << 9) + (((et << 5) + row) << 3)));
}

__global__ __launch_bounds__(256, 2)
void SwitchRouter_43078521979510_kernel(const float* __restrict__ x,
                                        const _Float16* __restrict__ wsp,
                                        const float* __restrict__ bias,
                                        float* __restrict__ out, int M)
{
    __shared__ float lds[16384];  // 64 KB: 4 waves x dbuf x (32x64 fp32); reused for reduction

    const int t = threadIdx.x;
    const int wv = t >> 6;
    const int lane = t & 63;
    const int row = lane & 31;     // A-row / B-col index within tile
    const int half_ = lane >> 5;   // k-group selector
    const int r0 = blockIdx.x * BM;
    const int kwb = wv * KPW;

    float* atile = lds + wv * (2 * 2048);
    const float* xg0 = x + (size_t)r0 * DIMK + kwb;

    floatx16 accP0 = {}, accQ0 = {}, accP1 = {}, accQ1 = {};
    half8 w0[4], w1[4];

    // prologue: stage chunks 0,1; load W frags for chunk0/ks0
    stage_chunk(xg0 + 0 * CHUNK, atile + 0 * 2048, lane);
    stage_chunk(xg0 + 1 * CHUNK, atile + 1 * 2048, lane);
    {
        int kg = kwb + 0;
        w0[0] = ldw(wsp, kg, half_, 0, 0, row);
        w0[1] = ldw(wsp, kg, half_, 0, 1, row);
        w0[2] = ldw(wsp, kg, half_, 1, 0, row);
        w0[3] = ldw(wsp, kg, half_, 1, 1, row);
    }

    for (int c = 0; c < NCHUNK; ++c) {
        // wait for chunk c's 8 global_load_lds to land.
        // steady state outstanding after: S_A(c+1)=8 + W(c,ks0)=4 -> 12; last chunk: only W=4.
        if (c == NCHUNK - 1) {
            asm volatile("s_waitcnt vmcnt(4)" ::: "memory");
        } else {
            asm volatile("s_waitcnt vmcnt(12)" ::: "memory");
        }
        const float* buf = atile + (c & 1) * 2048;

#pragma unroll
        for (int ks = 0; ks < NKS; ++ks) {
            // prefetch W frags for next kstep (or next chunk's ks0)
            const bool last = (c == NCHUNK - 1) && (ks == NKS - 1);
            if (!last) {
                int kgn = (ks == NKS - 1) ? (kwb + (c + 1) * CHUNK)
                                          : (kwb + c * CHUNK + (ks + 1) * KSTEP);
                if ((ks & 1) == 0) {
                    w1[0] = ldw(wsp, kgn, half_, 0, 0, row);
                    w1[1] = ldw(wsp, kgn, half_, 0, 1, row);
                    w1[2] = ldw(wsp, kgn, half_, 1, 0, row);
                    w1[3] = ldw(wsp, kgn, half_, 1, 1, row);
                } else {
                    w0[0] = ldw(wsp, kgn, half_, 0, 0, row);
                    w0[1] = ldw(wsp, kgn, half_, 0, 1, row);
                    w0[2] = ldw(wsp, kgn, half_, 1, 0, row);
                    w0[3] = ldw(wsp, kgn, half_, 1, 1, row);
                }
            }

            // A fragment: 8 fp32 of this lane's row, swizzled granules
            int g = ks * 4 + half_ * 2;
            int s0 = g ^ (row & 15);
            int s1 = (g + 1) ^ (row & 15);
            float4 fa = *(const float4*)&buf[row * 64 + s0 * 4];
            float4 fb = *(const float4*)&buf[row * 64 + s1 * 4];
            float f[8] = {fa.x, fa.y, fa.z, fa.w, fb.x, fb.y, fb.z, fb.w};
            half8 a0, a1;
#pragma unroll
            for (int i = 0; i < 8; ++i) {
                _Float16 h = (_Float16)f[i];
                a0[i] = h;
                a1[i] = (_Float16)(f[i] - (float)h);
            }

            const half8* wb = ((ks & 1) == 0) ? w0 : w1;
            accP0 = __builtin_amdgcn_mfma_f32_32x32x16_f16(a0, wb[0], accP0, 0, 0, 0);
            accQ0 = __builtin_amdgcn_mfma_f32_32x32x16_f16(a0, wb[1], accQ0, 0, 0, 0);
            accP1 = __builtin_amdgcn_mfma_f32_32x32x16_f16(a0, wb[2], accP1, 0, 0, 0);
            accQ1 = __builtin_amdgcn_mfma_f32_32x32x16_f16(a0, wb[3], accQ1, 0, 0, 0);
            accP0 = __builtin_amdgcn_mfma_f32_32x32x16_f16(a1, wb[1], accP0, 0, 0, 0);
            accQ0 = __builtin_amdgcn_mfma_f32_32x32x16_f16(a1, wb[0], accQ0, 0, 0, 0);
            accP1 = __builtin_amdgcn_mfma_f32_32x32x16_f16(a1, wb[3], accP1, 0, 0, 0);
            accQ1 = __builtin_amdgcn_mfma_f32_32x32x16_f16(a1, wb[2], accQ1, 0, 0, 0);
        }

        // ds_reads of this buffer done before it is restaged
        asm volatile("s_waitcnt lgkmcnt(0)" ::: "memory");
        if (c + 2 < NCHUNK) stage_chunk(xg0 + (c + 2) * CHUNK, atile + (c & 1) * 2048, lane);
    }

    // ---------------- cross-wave K reduction ----------------
    __syncthreads();
    // reduce buffer: [wave][32 rows][68 pad] fp32 = 8704 floats (aliases atile space)
    float* red = lds;
#pragma unroll
    for (int s = 0; s < 16; ++s) {
        int rowD = (s & 3) + 8 * (s >> 2) + 4 * half_;
        red[wv * 2176 + rowD * 68 + 0 * 32 + row] = accP0[s] + accQ0[s];
        red[wv * 2176 + rowD * 68 + 1 * 32 + row] = accP1[s] + accQ1[s];
    }
    __syncthreads();

    // ---------------- epilogue: bias + top-2 + softmax (round-1 validated) ----------------
    {
        const int rr = t >> 3;   // 0..31 row within block
        const int g8 = t & 7;    // expert-group 0..7
        float l[8];
#pragma unroll
        for (int j = 0; j < 8; ++j) {
            float s = 0.f;
#pragma unroll
            for (int w = 0; w < 4; ++w) s += red[w * 2176 + rr * 68 + g8 * 8 + j];
            l[j] = s + bias[g8 * 8 + j];
        }

        float v0 = l[0];
        int   i0 = 8 * g8;
        float v1 = -INFINITY;
        int   i1 = -1;
#pragma unroll
        for (int j = 1; j < 8; ++j) {
            const float lv = l[j];
            const int   e  = 8 * g8 + j;
            if (lv > v0) { v1 = v0; i1 = i0; v0 = lv; i0 = e; }
            else if (lv > v1) { v1 = lv; i1 = e; }
        }
#pragma unroll
        for (int m = 1; m <= 4; m <<= 1) {
            const float ov0 = __shfl_xor(v0, m);
            const int   oi0 = __shfl_xor(i0, m);
            const float ov1 = __shfl_xor(v1, m);
            const int   oi1 = __shfl_xor(i1, m);
            if (gt_pair(ov0, oi0, v0, i0)) {
                if (gt_pair(v0, i0, ov1, oi1)) { v1 = v0; i1 = i0; }
                else                           { v1 = ov1; i1 = oi1; }
                v0 = ov0; i0 = oi0;
            } else if (gt_pair(ov0, oi0, v1, i1)) {
                v1 = ov0; i1 = oi0;
            }
        }
        float d = 0.f;
#pragma unroll
        for (int j = 0; j < 8; ++j) d += expf(l[j] - v0);
#pragma unroll
        for (int m = 1; m <= 4; m <<= 1) d += __shfl_xor(d, m);

        if (g8 == 0) {
            const int R = r0 + rr;
            out[2 * R]     = (float)i0;
            out[2 * R + 1] = (float)i1;
            out[2 * M + 2 * R]     = 1.f / d;
            out[2 * M + 2 * R + 1] = expf(v1 - v0) / d;
        }
    }
}

extern "C" void kernel_launch(void* const* d_in, const int* in_sizes, int n_in,
                              void* d_out, int out_size, void* d_ws, size_t ws_size,
                              hipStream_t stream) {
    const float* x  = (const float*)d_in[0];
    const float* W  = (const float*)d_in[1];
    const float* b  = (const float*)d_in[2];
    float* out = (float*)d_out;
    _Float16* ws = (_Float16*)d_ws;
    const int M = in_sizes[0] / DIMK;   // 16384 rows

    SwitchRouter_wsplit<<<(NEXP * DIMK + 255) / 256, 256, 0, stream>>>(W, ws);
    SwitchRouter_43078521979510_kernel<<<M / BM, 256, 0, stream>>>(x, ws, b, out, M);
}